// Round 7
// baseline (29.508 us; speedup 1.0000x reference)
//
#include <hip/hip_runtime.h>

// Chamfer min-matching loss, B=8, P=4096, D=2, fp32.
// d2(q,g) = |q|^2 + (|g|^2 - 2 q.g). Per base point: hx=-2gx, hy=-2gy, c=|g|^2
// staged in LDS. Inner: 2 fma + 0.5 min3 per pair (v_fma_f32 + v_min3_f32).
// All per-query state in NAMED SCALARS (R5 lesson: arrays -> scratch).
// R7: QPT=8, grid 1024 blocks (4/CU, 16 waves/CU) for latency hiding.

#define NB    8
#define NP    4096
#define NC    32
#define NPC   2                      // query chunks: 4096 / (256*QPT)
#define QPT   8
#define CHUNK (NP / NC)              // 128
#define GRIDA (2 * NB * NC * NPC)    // 1024 blocks

typedef float f32x4 __attribute__((ext_vector_type(4)));

#define FOREACH_Q(M) M(0) M(1) M(2) M(3) M(4) M(5) M(6) M(7)

__global__ __launch_bounds__(256) void chamferA(const float* __restrict__ pred,
                                                const float* __restrict__ gt,
                                                float* __restrict__ pm,
                                                float* __restrict__ out) {
    __shared__ __align__(16) float shx[CHUNK];
    __shared__ __align__(16) float shy[CHUNK];
    __shared__ __align__(16) float sc[CHUNK];

    // zero the accumulator; stream order puts this before chamferB's atomics.
    if (blockIdx.x == 0 && threadIdx.x == 0) *out = 0.0f;

    int bid = blockIdx.x;
    int gc  = bid % NC;  bid /= NC;
    int pc  = bid % NPC; bid /= NPC;
    int b   = bid & 7;
    int dir = bid >> 3;            // 0: query=pred base=gt ; 1: query=gt base=pred

    const float* query = dir ? gt : pred;
    const float* base  = dir ? pred : gt;

    const float2* base2 = (const float2*)base + (size_t)b * NP + gc * CHUNK;
    int t = threadIdx.x;
    if (t < CHUNK) {
        float2 g = base2[t];
        shx[t] = -2.0f * g.x;
        shy[t] = -2.0f * g.y;
        sc[t]  = g.x * g.x + g.y * g.y;
    }
    __syncthreads();

    const float2* query2 = (const float2*)query + (size_t)b * NP + pc * (256 * QPT);
    const float INF = 3.402823466e+38f;

#define DECLQ(k) float px##k, py##k, m##k = INF; \
    { float2 q_ = query2[t + (k) * 256]; px##k = q_.x; py##k = q_.y; }
    FOREACH_Q(DECLQ)
#undef DECLQ

    const f32x4* hx4 = (const f32x4*)shx;
    const f32x4* hy4 = (const f32x4*)shy;
    const f32x4* cc4 = (const f32x4*)sc;

#pragma unroll 4
    for (int j = 0; j < CHUNK / 4; ++j) {
        f32x4 hx = hx4[j], hy = hy4[j], cc = cc4[j];
#define STEP(k) { \
        float d0_ = fmaf(px##k, hx.x, fmaf(py##k, hy.x, cc.x)); \
        float d1_ = fmaf(px##k, hx.y, fmaf(py##k, hy.y, cc.y)); \
        float d2_ = fmaf(px##k, hx.z, fmaf(py##k, hy.z, cc.z)); \
        float d3_ = fmaf(px##k, hx.w, fmaf(py##k, hy.w, cc.w)); \
        m##k = fminf(fminf(m##k, d0_), d1_);   /* v_min3_f32 */ \
        m##k = fminf(fminf(m##k, d2_), d3_); }
        FOREACH_Q(STEP)
#undef STEP
    }

    float* slot = pm + (((size_t)dir * NB + b) * NC + gc) * NP + pc * (256 * QPT) + t;
#define STORE(k) slot[(k) * 256] = fmaf(px##k, px##k, fmaf(py##k, py##k, m##k));
    FOREACH_Q(STORE)
#undef STORE
}

__global__ __launch_bounds__(256) void chamferB(const float* __restrict__ pm,
                                                float* __restrict__ out) {
    int idx  = blockIdx.x * 256 + threadIdx.x;   // 0 .. 2*NB*NP-1
    int dirb = idx >> 12;                        // dir*NB + b
    int q    = idx & (NP - 1);

    const float* p = pm + ((size_t)dirb * NC) * NP + q;
    float mv = p[0];
#pragma unroll
    for (int c = 1; c < NC; ++c) mv = fminf(mv, p[(size_t)c * NP]);

    float v = sqrtf(fmaxf(mv, 1e-12f));

#pragma unroll
    for (int o = 32; o > 0; o >>= 1) v += __shfl_down(v, o, 64);

    __shared__ float wsum[4];
    int lane = threadIdx.x & 63;
    int w    = threadIdx.x >> 6;
    if (lane == 0) wsum[w] = v;
    __syncthreads();
    if (threadIdx.x == 0) {
        float sblk = (wsum[0] + wsum[1]) + (wsum[2] + wsum[3]);
        atomicAdd(out, sblk * (0.5f / (float)(NB * NP)));
    }
}

extern "C" void kernel_launch(void* const* d_in, const int* in_sizes, int n_in,
                              void* d_out, int out_size, void* d_ws, size_t ws_size,
                              hipStream_t stream) {
    const float* pred = (const float*)d_in[0];
    const float* gt   = (const float*)d_in[1];
    float*       out  = (float*)d_out;
    float*       pm   = (float*)d_ws;            // 2*8*32*4096 f32 = 8 MiB

    (void)in_sizes; (void)n_in; (void)out_size; (void)ws_size;

    chamferA<<<GRIDA, 256, 0, stream>>>(pred, gt, pm, out);
    chamferB<<<(2 * NB * NP) / 256, 256, 0, stream>>>(pm, out);
}